// Round 2
// baseline (115.511 us; speedup 1.0000x reference)
//
#include <hip/hip_runtime.h>
#include <stdint.h>
#include <stddef.h>

#define B_   8
#define N_   256
#define H_   128
#define E_   128
#define MIDC 128
#define INZ  256
#define BIGN 1000000.0f

typedef float f32x4 __attribute__((ext_vector_type(4)));
typedef short bf16x8 __attribute__((ext_vector_type(8)));

static __device__ __forceinline__ short f2bf(float f) {
    unsigned u = __builtin_bit_cast(unsigned, f);
    unsigned r = (u + 0x7FFFu + ((u >> 16) & 1u)) >> 16;
    return (short)r;
}

// ---------------------------------------------------------------------------
// prep: msg1 = z@W1+b1 ; m2g = z@W2+b2+graph@Wg+bg ; zo1 = z@Wo1+bo1
// also (block 0): We^T -> bf16, XOR-swizzled for main-kernel B-frag reads
// 256 blocks x 256 threads, 8 rows/block
// ---------------------------------------------------------------------------
__global__ __launch_bounds__(256) void prep_kernel(
    const float* __restrict__ node, const float* __restrict__ hidden,
    const float* __restrict__ gf,
    const float* __restrict__ W1, const float* __restrict__ b1,
    const float* __restrict__ W2, const float* __restrict__ b2,
    const float* __restrict__ Wg, const float* __restrict__ bg,
    const float* __restrict__ Wo1, const float* __restrict__ bo1,
    const float* __restrict__ We,
    float* __restrict__ msg1, float* __restrict__ m2g,
    float* __restrict__ zo1, unsigned short* __restrict__ weT)
{
    __shared__ float zs[8][INZ];
    const int t  = threadIdx.x;
    const int r0 = blockIdx.x * 8;        // global row base (row = b*N + n)
    const int b  = r0 >> 8;

    for (int idx = t; idx < 8 * INZ; idx += 256) {
        int r = idx >> 8, k = idx & 255;
        int row = r0 + r;
        zs[r][k] = (k < H_) ? node[(size_t)row * H_ + k]
                            : hidden[(size_t)row * H_ + (k - H_)];
    }
    if (blockIdx.x == 0) {
        for (int e = t; e < 128 * 128; e += 256) {
            int n = e >> 7, k = e & 127;
            weT[(n * 128 + k) ^ ((n & 7) << 3)] =
                (unsigned short)f2bf(We[k * 128 + n]);
        }
    }
    __syncthreads();

    const int col = t & 127;
    const int rg  = t >> 7;              // 0..1, 4 rows each
    float a1[4] = {0, 0, 0, 0}, a2[4] = {0, 0, 0, 0}, ao[4] = {0, 0, 0, 0};

#pragma unroll 4
    for (int k = 0; k < INZ; ++k) {
        float w1 = W1[k * 128 + col];
        float w2 = W2[k * 128 + col];
        float wo = Wo1[k * 128 + col];
#pragma unroll
        for (int rr = 0; rr < 4; ++rr) {
            float zv = zs[rg * 4 + rr][k];
            a1[rr] = fmaf(zv, w1, a1[rr]);
            a2[rr] = fmaf(zv, w2, a2[rr]);
            ao[rr] = fmaf(zv, wo, ao[rr]);
        }
    }
    float mg = bg[col];
#pragma unroll 4
    for (int g = 0; g < 128; ++g)
        mg = fmaf(gf[b * 128 + g], Wg[g * 128 + col], mg);

    const float bb1 = b1[col], bb2 = b2[col], bbo = bo1[col];
#pragma unroll
    for (int rr = 0; rr < 4; ++rr) {
        size_t row = (size_t)(r0 + rg * 4 + rr);
        msg1[row * 128 + col] = a1[rr] + bb1;
        m2g[row * 128 + col]  = a2[rr] + bb2 + mg;
        zo1[row * 128 + col]  = ao[rr] + bbo;
    }
}

// ---------------------------------------------------------------------------
// main: per block (b, 4 j's): 8 i-tiles of 32 -> 128x128x128 bf16 MFMA tile,
// masked-max epilogue over i, fused relu(zo1 + (red+msg1+be)@Wo2 + bo2).
// 2-deep pipeline: tile it+1 prefetched into regs while tile it computes;
// raw s_barrier (no vmcnt drain) keeps prefetch loads in flight.
// ---------------------------------------------------------------------------
__global__ __launch_bounds__(256, 2) void pgn_main(
    const float* __restrict__ edge, const float* __restrict__ adj,
    const float* __restrict__ msg1, const float* __restrict__ m2g,
    const float* __restrict__ zo1,
    const unsigned short* __restrict__ weT,
    const float* __restrict__ be, const float* __restrict__ Wo2,
    const float* __restrict__ bo2, float* __restrict__ out)
{
    __shared__ __align__(16) short atile[128 * 128];   // 32KB edge tile (bf16, swizzled)
    __shared__ __align__(16) short wlds[128 * 128];    // 32KB WeT panel (pre-swizzled)
    __shared__ __align__(16) float adjt[128];          // 32 i x 4 j
    __shared__ __align__(16) float redb[512];          // 4 j x 128 cols

    const int t    = threadIdx.x;
    const int lane = t & 63, wid = t >> 6;
    const int wr   = wid >> 1, wn = wid & 1;
    const int hi   = lane >> 4, c15 = lane & 15;
    const int blk  = blockIdx.x;
    const int b    = blk >> 6, jt = blk & 63;
    const int j0   = jt * 4;

    // staging geometry: thread t covers tile-row sr (= 4*i_loc+jj), half sh
    const int sr = t >> 1, sh = t & 1;
    const size_t base0 = (((size_t)(b * N_) + (sr >> 2)) * N_ + (j0 + (sr & 3))) * E_
                         + (size_t)sh * 64;
    const int wbase = sr * 256 + sh * 128;   // LDS byte base
    const int swz   = (sr & 7) << 4;

    // ---- prologue: issue WeT loads, tile-0 prefetch, adj-0 prefetch ----
    uint4 wreg[8];
    {
        const uint4* wsrc = (const uint4*)weT;
#pragma unroll
        for (int q = 0; q < 8; ++q) wreg[q] = wsrc[t + 256 * q];
    }
    float4 pf[16];
    {
        const float4* s4 = (const float4*)(edge + base0);
#pragma unroll
        for (int q = 0; q < 16; ++q) pf[q] = s4[q];
    }
    float adjv = 0.0f;
    if (t < 128)
        adjv = adj[(size_t)(b * N_ + (t >> 2)) * N_ + j0 + (t & 3)];

    {
        uint4* wd = (uint4*)wlds;
#pragma unroll
        for (int q = 0; q < 8; ++q) wd[t + 256 * q] = wreg[q];
    }
    asm volatile("s_waitcnt lgkmcnt(0)" ::: "memory");
    __builtin_amdgcn_s_barrier();
    __builtin_amdgcn_sched_barrier(0);

    float rmax[4][4];
#pragma unroll
    for (int n = 0; n < 4; ++n)
#pragma unroll
        for (int rg = 0; rg < 4; ++rg) rmax[n][rg] = -BIGN;

    for (int it = 0; it < 8; ++it) {
        // ---- stage tile it from pf regs: f32 -> bf16 -> swizzled LDS ----
#pragma unroll
        for (int q = 0; q < 8; ++q) {
            float4 f0 = pf[2 * q];
            float4 f1 = pf[2 * q + 1];
            bf16x8 s;
            s[0] = f2bf(f0.x); s[1] = f2bf(f0.y); s[2] = f2bf(f0.z); s[3] = f2bf(f0.w);
            s[4] = f2bf(f1.x); s[5] = f2bf(f1.y); s[6] = f2bf(f1.z); s[7] = f2bf(f1.w);
            *(bf16x8*)((char*)atile + ((wbase + q * 16) ^ swz)) = s;
        }
        if (t < 128) adjt[t] = adjv;
        asm volatile("s_waitcnt lgkmcnt(0)" ::: "memory");
        __builtin_amdgcn_s_barrier();            // tile ready (no vmcnt drain)
        __builtin_amdgcn_sched_barrier(0);

        // ---- prefetch tile it+1 (stays in flight across MFMA + barriers) ----
        if (it < 7) {
            const float4* s4 = (const float4*)(edge + base0 + (size_t)(it + 1) * 32 * (N_ * E_));
#pragma unroll
            for (int q = 0; q < 16; ++q) pf[q] = s4[q];
            if (t < 128)
                adjv = adj[(size_t)(b * N_ + (it + 1) * 32 + (t >> 2)) * N_ + j0 + (t & 3)];
        }

        // ---- hoist m2g values (overlap with MFMA) ----
        float mv[4][4];
#pragma unroll
        for (int m = 0; m < 4; ++m) {
            int i_loc = wr * 16 + m * 4 + hi;
            const float* mp = m2g + (size_t)(b * N_ + it * 32 + i_loc) * 128 + wn * 64 + c15;
#pragma unroll
            for (int n = 0; n < 4; ++n) mv[m][n] = mp[n * 16];
        }

        // ---- 128x128x128 tile GEMM: 4 K-steps of 32 ----
        f32x4 acc[4][4] = {};
#pragma unroll
        for (int ks = 0; ks < 4; ++ks) {
            bf16x8 af[4], bfv[4];
#pragma unroll
            for (int m = 0; m < 4; ++m) {
                int rowA = wr * 64 + m * 16 + c15;
                int a = (rowA * 256 + ks * 64 + hi * 16) ^ ((rowA & 7) << 4);
                af[m] = *(const bf16x8*)((const char*)atile + a);
            }
#pragma unroll
            for (int n = 0; n < 4; ++n) {
                int rowB = wn * 64 + n * 16 + c15;
                int a = (rowB * 256 + ks * 64 + hi * 16) ^ ((rowB & 7) << 4);
                bfv[n] = *(const bf16x8*)((const char*)wlds + a);
            }
#pragma unroll
            for (int m = 0; m < 4; ++m)
#pragma unroll
                for (int n = 0; n < 4; ++n)
                    acc[m][n] = __builtin_amdgcn_mfma_f32_16x16x32_bf16(
                        af[m], bfv[n], acc[m][n], 0, 0, 0);
        }

        // ---- epilogue: masked max over i into running registers ----
#pragma unroll
        for (int m = 0; m < 4; ++m) {
            int i_loc = wr * 16 + m * 4 + hi;
            f32x4 am = *(const f32x4*)&adjt[i_loc * 4];
#pragma unroll
            for (int n = 0; n < 4; ++n) {
#pragma unroll
                for (int rg = 0; rg < 4; ++rg) {              // rg == jj
                    float v = acc[m][n][rg] + mv[m][n];
                    v = (am[rg] > 0.0f) ? v : -BIGN;
                    rmax[n][rg] = fmaxf(rmax[n][rg], v);
                }
            }
        }
        __builtin_amdgcn_s_barrier();            // release atile/adjt
        __builtin_amdgcn_sched_barrier(0);
    }

    // ---- reduce across hi (lanes) and wr (waves) ----
#pragma unroll
    for (int n = 0; n < 4; ++n)
#pragma unroll
        for (int rg = 0; rg < 4; ++rg) {
            float v = rmax[n][rg];
            v = fmaxf(v, __shfl_xor(v, 16, 64));
            v = fmaxf(v, __shfl_xor(v, 32, 64));
            rmax[n][rg] = v;
        }
    if (wr == 0 && lane < 16) {
#pragma unroll
        for (int n = 0; n < 4; ++n)
#pragma unroll
            for (int rg = 0; rg < 4; ++rg)
                redb[rg * 128 + wn * 64 + n * 16 + c15] = rmax[n][rg];
    }
    __syncthreads();
    if (wr == 1 && lane < 16) {
#pragma unroll
        for (int n = 0; n < 4; ++n)
#pragma unroll
            for (int rg = 0; rg < 4; ++rg) {
                int e = rg * 128 + wn * 64 + n * 16 + c15;
                redb[e] = fmaxf(redb[e], rmax[n][rg]);
            }
    }
    __syncthreads();

    // ---- add j-constant terms: msg1 + be ----
    for (int e = t; e < 512; e += 256) {
        int jj = e >> 7, k = e & 127;
        redb[e] += msg1[(size_t)(b * N_ + j0 + jj) * 128 + k] + be[k];
    }
    __syncthreads();

    // ---- fused output: relu(zo1 + red@Wo2 + bo2), 4 rows x 128 cols ----
    {
        const int col = t & 127;
        const int jh  = t >> 7;
#pragma unroll
        for (int jx = 0; jx < 2; ++jx) {
            int jj = jh * 2 + jx;
            size_t row = (size_t)(b * N_ + j0 + jj);
            float a = 0.0f;
#pragma unroll 8
            for (int k = 0; k < 128; ++k)
                a = fmaf(redb[jj * 128 + k], Wo2[k * 128 + col], a);
            float o = zo1[row * 128 + col] + bo2[col] + a;
            out[row * 128 + col] = fmaxf(o, 0.0f);
        }
    }
}

extern "C" void kernel_launch(void* const* d_in, const int* in_sizes, int n_in,
                              void* d_out, int out_size, void* d_ws, size_t ws_size,
                              hipStream_t stream) {
    const float* node   = (const float*)d_in[0];
    const float* edge   = (const float*)d_in[1];
    const float* gf     = (const float*)d_in[2];
    const float* adj    = (const float*)d_in[3];
    const float* hidden = (const float*)d_in[4];
    const float* W1  = (const float*)d_in[5];
    const float* b1  = (const float*)d_in[6];
    const float* W2  = (const float*)d_in[7];
    const float* b2  = (const float*)d_in[8];
    const float* We  = (const float*)d_in[9];
    const float* be  = (const float*)d_in[10];
    const float* Wg  = (const float*)d_in[11];
    const float* bg  = (const float*)d_in[12];
    const float* Wo1 = (const float*)d_in[13];
    const float* bo1 = (const float*)d_in[14];
    const float* Wo2 = (const float*)d_in[15];
    const float* bo2 = (const float*)d_in[16];
    float* out = (float*)d_out;

    float* msg1 = (float*)d_ws;
    float* m2g  = msg1 + 2048 * 128;
    float* zo1  = m2g + 2048 * 128;
    unsigned short* weT = (unsigned short*)(zo1 + 2048 * 128);

    hipLaunchKernelGGL(prep_kernel, dim3(256), dim3(256), 0, stream,
                       node, hidden, gf, W1, b1, W2, b2, Wg, bg, Wo1, bo1, We,
                       msg1, m2g, zo1, weT);
    hipLaunchKernelGGL(pgn_main, dim3(512), dim3(256), 0, stream,
                       edge, adj, msg1, m2g, zo1, weT, be, Wo2, bo2, out);
}

// Round 3
// 109.994 us; speedup vs baseline: 1.0502x; 1.0502x over previous
//
#include <hip/hip_runtime.h>
#include <hip/hip_bf16.h>
#include <stdint.h>
#include <stddef.h>

#define B_   8
#define N_   256
#define H_   128
#define E_   128
#define INZ  256
#define BIGN 1000000.0f

typedef float f32x4 __attribute__((ext_vector_type(4)));
typedef short bf16x8 __attribute__((ext_vector_type(8)));

static __device__ __forceinline__ unsigned cvt2(float a, float b) {
    // native RNE cvt (compiler emits v_cvt_pk_bf16_f32 / packs)
    unsigned short ra = __builtin_bit_cast(unsigned short, __float2bfloat16(a));
    unsigned short rb = __builtin_bit_cast(unsigned short, __float2bfloat16(b));
    return (unsigned)ra | ((unsigned)rb << 16);
}

// ---------------------------------------------------------------------------
// prep: msg1 = z@W1+b1 ; m2g = z@W2+b2+graph@Wg+bg ; zo1 = z@Wo1+bo1
// blocks 0..7 also produce We^T -> bf16, XOR-pre-swizzled (2048 elems each)
// 512 blocks x 256 threads, 4 rows/block (8 waves/CU for latency hiding)
// ---------------------------------------------------------------------------
__global__ __launch_bounds__(256) void prep_kernel(
    const float* __restrict__ node, const float* __restrict__ hidden,
    const float* __restrict__ gf,
    const float* __restrict__ W1, const float* __restrict__ b1,
    const float* __restrict__ W2, const float* __restrict__ b2,
    const float* __restrict__ Wg, const float* __restrict__ bg,
    const float* __restrict__ Wo1, const float* __restrict__ bo1,
    const float* __restrict__ We,
    float* __restrict__ msg1, float* __restrict__ m2g,
    float* __restrict__ zo1, unsigned short* __restrict__ weT)
{
    __shared__ float zs[4][INZ];
    const int t  = threadIdx.x;
    const int r0 = blockIdx.x * 4;        // global row base (row = b*N + n)
    const int b  = r0 >> 8;

    for (int idx = t; idx < 4 * INZ; idx += 256) {
        int r = idx >> 8, k = idx & 255;
        int row = r0 + r;
        zs[r][k] = (k < H_) ? node[(size_t)row * H_ + k]
                            : hidden[(size_t)row * H_ + (k - H_)];
    }
    // We^T bf16, pre-swizzled: weT[(n*128+k) ^ ((n&7)<<3)] = bf16(We[k][n])
    if (blockIdx.x < 8) {
        int e0 = blockIdx.x * 2048;
        for (int e = e0 + t; e < e0 + 2048; e += 256) {
            int n = e >> 7, k = e & 127;
            weT[(n * 128 + k) ^ ((n & 7) << 3)] =
                (unsigned short)__builtin_bit_cast(unsigned short,
                    __float2bfloat16(We[k * 128 + n]));
        }
    }
    __syncthreads();

    const int col = t & 127;
    const int rg  = t >> 7;              // 0..1, 2 rows each
    float a1[2] = {0, 0}, a2[2] = {0, 0}, ao[2] = {0, 0};

#pragma unroll 4
    for (int k = 0; k < INZ; ++k) {
        float w1 = W1[k * 128 + col];
        float w2 = W2[k * 128 + col];
        float wo = Wo1[k * 128 + col];
#pragma unroll
        for (int rr = 0; rr < 2; ++rr) {
            float zv = zs[rg * 2 + rr][k];
            a1[rr] = fmaf(zv, w1, a1[rr]);
            a2[rr] = fmaf(zv, w2, a2[rr]);
            ao[rr] = fmaf(zv, wo, ao[rr]);
        }
    }
    float mg = bg[col];
#pragma unroll 4
    for (int g = 0; g < 128; ++g)
        mg = fmaf(gf[b * 128 + g], Wg[g * 128 + col], mg);

    const float bb1 = b1[col], bb2 = b2[col], bbo = bo1[col];
#pragma unroll
    for (int rr = 0; rr < 2; ++rr) {
        size_t row = (size_t)(r0 + rg * 2 + rr);
        msg1[row * 128 + col] = a1[rr] + bb1;
        m2g[row * 128 + col]  = a2[rr] + bb2 + mg;
        zo1[row * 128 + col]  = ao[rr] + bbo;
    }
}

// ---------------------------------------------------------------------------
// main: 512*nsplit blocks. Block = (jblk = b*64+jt, ih). Tile = 16 i x 4 j
// rows(64) x K=128 bf16 MFMA; masked running max over i; partial max -> redp.
// Staging is wave-contiguous: one wave instruction = 1KB contiguous global.
// LDS 48KB + VGPR<=170 -> 3 blocks/CU resident (desync overlap).
// ---------------------------------------------------------------------------
__global__ __launch_bounds__(256, 3) void pgn_main(
    const float* __restrict__ edge, const float* __restrict__ adj,
    const float* __restrict__ m2g,
    const unsigned short* __restrict__ weT,
    float* __restrict__ redp, int nsplit)
{
    __shared__ __align__(16) short atile[64 * 128];    // 16KB edge tile (bf16, swizzled)
    __shared__ __align__(16) short wlds[128 * 128];    // 32KB WeT panel (pre-swizzled)

    const int t    = threadIdx.x;
    const int lane = t & 63, wid = t >> 6;
    const int wr   = wid >> 1, wn = wid & 1;
    const int hi   = lane >> 4, c15 = lane & 15;
    const int blk  = blockIdx.x;
    const int ih   = blk % nsplit;
    const int jblk = blk / nsplit;
    const int b    = jblk >> 6, jt = jblk & 63;
    const int j0   = jt * 4;
    const int irange = N_ / nsplit;
    const int ibase  = ih * irange;
    const int ntiles = irange >> 4;       // tiles of 16 i

    // ---- copy WeT panel into LDS (wave-contiguous uint4) ----
    {
        const uint4* wsrc = (const uint4*)weT;
        uint4* wd = (uint4*)wlds;
#pragma unroll
        for (int q = 0; q < 8; ++q) wd[t + 256 * q] = wsrc[t + 256 * q];
    }

    // ---- staging geometry (wave-contiguous): g = q*256 + t ----
    // th = i_loc&1 source, jj, f4col constant per thread; i_loc = 2q + th
    const int th    = t >> 7;
    const int jj_s  = (t >> 5) & 3;
    const int f4c   = t & 31;
    const size_t gbase0 = (((size_t)(b * N_) + ibase + th) * N_ + (j0 + jj_s)) * E_
                          + (size_t)f4c * 4;
    const size_t qstep  = (size_t)2 * N_ * E_;     // i += 2 per q
    const int r0c = 4 * th + jj_s;                 // row mod 8
    char* lbase = (char*)atile + r0c * 256 + ((f4c * 8) ^ (r0c << 4));

    float rmax[4][4];
#pragma unroll
    for (int n = 0; n < 4; ++n)
#pragma unroll
        for (int rg = 0; rg < 4; ++rg) rmax[n][rg] = -BIGN;

    __syncthreads();    // wlds ready

    for (int it = 0; it < ntiles; ++it) {
        // ---- stage tile: 8x 16B contiguous-per-wave loads, cvt, LDS ----
        const float* gsrc = edge + gbase0 + (size_t)it * 16 * N_ * E_;
        float4 f[8];
#pragma unroll
        for (int q = 0; q < 8; ++q)
            f[q] = *(const float4*)(gsrc + q * qstep);
#pragma unroll
        for (int q = 0; q < 8; ++q) {
            uint2 s;
            s.x = cvt2(f[q].x, f[q].y);
            s.y = cvt2(f[q].z, f[q].w);
            *(uint2*)(lbase + q * 2048) = s;
        }
        __syncthreads();

        // ---- hoist adj + m2g (latency hides under MFMA) ----
        float am[2][4], mv[2][4];
#pragma unroll
        for (int m = 0; m < 2; ++m) {
            int ig = ibase + it * 16 + wr * 8 + m * 4 + hi;
            f32x4 a4 = *(const f32x4*)(adj + (size_t)(b * N_ + ig) * N_ + j0);
#pragma unroll
            for (int rg = 0; rg < 4; ++rg) am[m][rg] = a4[rg];
            const float* mp = m2g + (size_t)(b * N_ + ig) * 128 + wn * 64 + c15;
#pragma unroll
            for (int n = 0; n < 4; ++n) mv[m][n] = mp[n * 16];
        }

        // ---- 64x128x128 tile GEMM: 4 K-steps of 32 ----
        f32x4 acc[2][4] = {};
#pragma unroll
        for (int ks = 0; ks < 4; ++ks) {
            bf16x8 af[2], bfv[4];
#pragma unroll
            for (int m = 0; m < 2; ++m) {
                int rowA = wr * 32 + m * 16 + c15;
                int a = (rowA * 256 + ks * 64 + hi * 16) ^ ((rowA & 7) << 4);
                af[m] = *(const bf16x8*)((const char*)atile + a);
            }
#pragma unroll
            for (int n = 0; n < 4; ++n) {
                int rowB = wn * 64 + n * 16 + c15;
                int a = (rowB * 256 + ks * 64 + hi * 16) ^ ((rowB & 7) << 4);
                bfv[n] = *(const bf16x8*)((const char*)wlds + a);
            }
#pragma unroll
            for (int m = 0; m < 2; ++m)
#pragma unroll
                for (int n = 0; n < 4; ++n)
                    acc[m][n] = __builtin_amdgcn_mfma_f32_16x16x32_bf16(
                        af[m], bfv[n], acc[m][n], 0, 0, 0);
        }
        __syncthreads();   // frag reads done; next stage may overwrite

        // ---- epilogue: masked max over i (registers/global only) ----
#pragma unroll
        for (int m = 0; m < 2; ++m) {
#pragma unroll
            for (int n = 0; n < 4; ++n) {
#pragma unroll
                for (int rg = 0; rg < 4; ++rg) {           // rg == jj
                    float v = acc[m][n][rg] + mv[m][n];
                    v = (am[m][rg] > 0.0f) ? v : -BIGN;
                    rmax[n][rg] = fmaxf(rmax[n][rg], v);
                }
            }
        }
    }

    // ---- reduce across hi lanes, then across wr waves via LDS ----
#pragma unroll
    for (int n = 0; n < 4; ++n)
#pragma unroll
        for (int rg = 0; rg < 4; ++rg) {
            float v = rmax[n][rg];
            v = fmaxf(v, __shfl_xor(v, 16, 64));
            v = fmaxf(v, __shfl_xor(v, 32, 64));
            rmax[n][rg] = v;
        }
    float* redb = (float*)atile;     // alias (all tile work done)
    if (wr == 0 && lane < 16) {
#pragma unroll
        for (int n = 0; n < 4; ++n)
#pragma unroll
            for (int rg = 0; rg < 4; ++rg)
                redb[rg * 128 + wn * 64 + n * 16 + c15] = rmax[n][rg];
    }
    __syncthreads();
    if (wr == 1 && lane < 16) {
#pragma unroll
        for (int n = 0; n < 4; ++n)
#pragma unroll
            for (int rg = 0; rg < 4; ++rg) {
                int e = rg * 128 + wn * 64 + n * 16 + c15;
                redb[e] = fmaxf(redb[e], rmax[n][rg]);
            }
    }
    __syncthreads();
#pragma unroll
    for (int e = t; e < 512; e += 256)
        redp[(size_t)blk * 512 + e] = redb[e];
}

// ---------------------------------------------------------------------------
// finish: red = max over parts; out = relu(zo1 + (red+msg1+be)@Wo2 + bo2)
// 256 blocks x 256 threads, 8 rows/block
// ---------------------------------------------------------------------------
__global__ __launch_bounds__(256) void finish_kernel(
    const float* __restrict__ redp, const float* __restrict__ msg1,
    const float* __restrict__ zo1, const float* __restrict__ be,
    const float* __restrict__ Wo2, const float* __restrict__ bo2,
    float* __restrict__ out, int nsplit)
{
    __shared__ float rb[8][128];
    const int t  = threadIdx.x;
    const int r0 = blockIdx.x * 8;

    for (int idx = t; idx < 1024; idx += 256) {
        int rr = idx >> 7, k = idx & 127;
        int r = r0 + rr;
        int jblk = r >> 2, jj = r & 3;
        float v = -BIGN - 1.0f;
        for (int p = 0; p < nsplit; ++p)
            v = fmaxf(v, redp[(size_t)(jblk * nsplit + p) * 512 + jj * 128 + k]);
        rb[rr][k] = v + msg1[(size_t)r * 128 + k] + be[k];
    }
    __syncthreads();

    const int col = t & 127;
    const int half = t >> 7;
#pragma unroll
    for (int rx = 0; rx < 4; ++rx) {
        int rr = half * 4 + rx;
        size_t row = (size_t)(r0 + rr);
        float a = 0.0f;
#pragma unroll 8
        for (int k = 0; k < 128; ++k)
            a = fmaf(rb[rr][k], Wo2[k * 128 + col], a);
        float o = zo1[row * 128 + col] + bo2[col] + a;
        out[row * 128 + col] = fmaxf(o, 0.0f);
    }
}

extern "C" void kernel_launch(void* const* d_in, const int* in_sizes, int n_in,
                              void* d_out, int out_size, void* d_ws, size_t ws_size,
                              hipStream_t stream) {
    const float* node   = (const float*)d_in[0];
    const float* edge   = (const float*)d_in[1];
    const float* gf     = (const float*)d_in[2];
    const float* adj    = (const float*)d_in[3];
    const float* hidden = (const float*)d_in[4];
    const float* W1  = (const float*)d_in[5];
    const float* b1  = (const float*)d_in[6];
    const float* W2  = (const float*)d_in[7];
    const float* b2  = (const float*)d_in[8];
    const float* We  = (const float*)d_in[9];
    const float* be  = (const float*)d_in[10];
    const float* Wg  = (const float*)d_in[11];
    const float* bg  = (const float*)d_in[12];
    const float* Wo1 = (const float*)d_in[13];
    const float* bo1 = (const float*)d_in[14];
    const float* Wo2 = (const float*)d_in[15];
    const float* bo2 = (const float*)d_in[16];
    float* out = (float*)d_out;

    float* msg1 = (float*)d_ws;                        // 1 MB
    float* m2g  = msg1 + 2048 * 128;                   // 1 MB
    float* zo1  = m2g + 2048 * 128;                    // 1 MB
    unsigned short* weT = (unsigned short*)(zo1 + 2048 * 128);   // 32 KB
    float* redp = (float*)((char*)weT + 128 * 128 * sizeof(unsigned short));

    // nsplit=2 -> 1024 blocks (4 queued/CU, 3 resident). Fall back if ws small.
    const size_t base_bytes = 3u * 1048576u + 32768u;
    int nsplit = (ws_size >= base_bytes + 2u * 1048576u) ? 2 : 1;

    hipLaunchKernelGGL(prep_kernel, dim3(512), dim3(256), 0, stream,
                       node, hidden, gf, W1, b1, W2, b2, Wg, bg, Wo1, bo1, We,
                       msg1, m2g, zo1, weT);
    hipLaunchKernelGGL(pgn_main, dim3(512 * nsplit), dim3(256), 0, stream,
                       edge, adj, m2g, weT, redp, nsplit);
    hipLaunchKernelGGL(finish_kernel, dim3(256), dim3(256), 0, stream,
                       redp, msg1, zo1, be, Wo2, bo2, out, nsplit);
}

// Round 4
// 106.185 us; speedup vs baseline: 1.0878x; 1.0359x over previous
//
#include <hip/hip_runtime.h>
#include <hip/hip_bf16.h>
#include <stdint.h>
#include <stddef.h>

#define B_   8
#define N_   256
#define H_   128
#define E_   128
#define INZ  256
#define BIGN 1000000.0f

typedef float f32x4 __attribute__((ext_vector_type(4)));
typedef short bf16x8 __attribute__((ext_vector_type(8)));

static __device__ __forceinline__ unsigned cvt2(float a, float b) {
    unsigned short ra = __builtin_bit_cast(unsigned short, __float2bfloat16(a));
    unsigned short rb = __builtin_bit_cast(unsigned short, __float2bfloat16(b));
    return (unsigned)ra | ((unsigned)rb << 16);
}

static __device__ __forceinline__ bf16x8 mk_frag(f32x4 lo, f32x4 h4) {
    union { unsigned u[4]; bf16x8 v; } r;
    r.u[0] = cvt2(lo.x, lo.y);
    r.u[1] = cvt2(lo.z, lo.w);
    r.u[2] = cvt2(h4.x, h4.y);
    r.u[3] = cvt2(h4.z, h4.w);
    return r.v;
}

// async global->LDS, 16B per lane, LDS dest = wave-uniform base + lane*16
#define GL16(gp, lp) __builtin_amdgcn_global_load_lds(                        \
    (const __attribute__((address_space(1))) unsigned int*)(gp),              \
    (__attribute__((address_space(3))) unsigned int*)(lp), 16, 0, 0)

// ---------------------------------------------------------------------------
// prep: msg1 = z@W1+b1 ; m2g = z@W2+b2+graph@Wg+bg ; zo1 = z@Wo1+bo1
// blocks 0..7 also produce We^T -> bf16, XOR-pre-swizzled
// ---------------------------------------------------------------------------
__global__ __launch_bounds__(256) void prep_kernel(
    const float* __restrict__ node, const float* __restrict__ hidden,
    const float* __restrict__ gf,
    const float* __restrict__ W1, const float* __restrict__ b1,
    const float* __restrict__ W2, const float* __restrict__ b2,
    const float* __restrict__ Wg, const float* __restrict__ bg,
    const float* __restrict__ Wo1, const float* __restrict__ bo1,
    const float* __restrict__ We,
    float* __restrict__ msg1, float* __restrict__ m2g,
    float* __restrict__ zo1, unsigned short* __restrict__ weT)
{
    __shared__ float zs[4][INZ];
    const int t  = threadIdx.x;
    const int r0 = blockIdx.x * 4;
    const int b  = r0 >> 8;

    for (int idx = t; idx < 4 * INZ; idx += 256) {
        int r = idx >> 8, k = idx & 255;
        int row = r0 + r;
        zs[r][k] = (k < H_) ? node[(size_t)row * H_ + k]
                            : hidden[(size_t)row * H_ + (k - H_)];
    }
    if (blockIdx.x < 8) {
        int e0 = blockIdx.x * 2048;
        for (int e = e0 + t; e < e0 + 2048; e += 256) {
            int n = e >> 7, k = e & 127;
            weT[(n * 128 + k) ^ ((n & 7) << 3)] =
                (unsigned short)__builtin_bit_cast(unsigned short,
                    __float2bfloat16(We[k * 128 + n]));
        }
    }
    __syncthreads();

    const int col = t & 127;
    const int rg  = t >> 7;
    float a1[2] = {0, 0}, a2[2] = {0, 0}, ao[2] = {0, 0};

#pragma unroll 4
    for (int k = 0; k < INZ; ++k) {
        float w1 = W1[k * 128 + col];
        float w2 = W2[k * 128 + col];
        float wo = Wo1[k * 128 + col];
#pragma unroll
        for (int rr = 0; rr < 2; ++rr) {
            float zv = zs[rg * 2 + rr][k];
            a1[rr] = fmaf(zv, w1, a1[rr]);
            a2[rr] = fmaf(zv, w2, a2[rr]);
            ao[rr] = fmaf(zv, wo, ao[rr]);
        }
    }
    float mg = bg[col];
#pragma unroll 4
    for (int g = 0; g < 128; ++g)
        mg = fmaf(gf[b * 128 + g], Wg[g * 128 + col], mg);

    const float bb1 = b1[col], bb2 = b2[col], bbo = bo1[col];
#pragma unroll
    for (int rr = 0; rr < 2; ++rr) {
        size_t row = (size_t)(r0 + rg * 2 + rr);
        msg1[row * 128 + col] = a1[rr] + bb1;
        m2g[row * 128 + col]  = a2[rr] + bb2 + mg;
        zo1[row * 128 + col]  = ao[rr] + bbo;
    }
}

// ---------------------------------------------------------------------------
// main: block = (jblk, ih). Tile = 8 i x 4 j = 32 rows x K=128.
// 3-buffer LDS ring, global_load_lds DMA staging (swizzled SOURCE, linear
// dest), ONE raw s_barrier per tile, counted vmcnt(9) -> next tile's loads
// stay in flight across barrier + MFMA. B-frags (WeT) live in 64 VGPRs.
// ---------------------------------------------------------------------------
__global__ __launch_bounds__(256, 3) void pgn_main(
    const float* __restrict__ edge, const float* __restrict__ adj,
    const float* __restrict__ m2g, const unsigned short* __restrict__ weT,
    float* __restrict__ redp, int nsplit)
{
    __shared__ __align__(16) char smem[49152];   // 3 x 16KB ring

    const int t    = threadIdx.x;
    const int lane = t & 63, wid = t >> 6;
    const int wr   = wid >> 1, wn = wid & 1;
    const int hi   = lane >> 4, c15 = lane & 15;
    const int blk  = blockIdx.x;
    const int ih   = blk % nsplit;
    const int jblk = blk / nsplit;
    const int b    = jblk >> 6, jt = jblk & 63;
    const int j0   = jt * 4;
    const int irange = N_ / nsplit;
    const int ibase  = ih * irange;
    const int nt     = irange >> 3;          // tiles of 8 i

    // ---- B fragments from pre-swizzled weT: 4 n x 4 ks = 64 VGPR ----
    bf16x8 bfr[4][4];
#pragma unroll
    for (int n = 0; n < 4; ++n) {
        int col = wn * 64 + n * 16 + c15;
        int sw  = (col & 7) << 3;
#pragma unroll
        for (int ks = 0; ks < 4; ++ks) {
            int sidx = (col * 128 + ks * 32 + hi * 8) ^ sw;
            bfr[n][ks] = *(const bf16x8*)(weT + sidx);
        }
    }

    // ---- stage addressing: wave wid stages tile-rows wid*8 + 2q + (lane>>5)
    // LDS linear row-major [32][512B]; source per-lane XOR-preswizzled so a
    // consumer read at (x ^ ((row&7)<<4)) returns linear data (rule #21).
    const int l2 = lane >> 5;
    const int wb = (lane & 31) * 16;
    const char* gq0; const char* gq1; const char* gq2; const char* gq3;
    {
        const char* eb = (const char*)edge;
#pragma unroll
        for (int q = 0; q < 4; ++q) {
            int tr = wid * 8 + 2 * q + l2;
            int il = tr >> 2, jj = tr & 3;
            int sb = wb ^ ((tr & 7) << 4);
            const char* g = eb +
                (((size_t)(b * N_) + ibase + il) * N_ + (j0 + jj)) * 512 + sb;
            if (q == 0) gq0 = g; else if (q == 1) gq1 = g;
            else if (q == 2) gq2 = g; else gq3 = g;
        }
    }
    const unsigned woff = (unsigned)__builtin_amdgcn_readfirstlane(wid * 4096);

    char* pa = smem;
    char* pb = smem + 16384;
    char* pc = smem + 32768;

    // prologue: stage tile 0 into pa
    GL16(gq0, pa + woff);
    GL16(gq1, pa + woff + 1024);
    GL16(gq2, pa + woff + 2048);
    GL16(gq3, pa + woff + 3072);

    // consumer A-frag base: row tr = wr*16 + c15, swizzled
    const int trc = wr * 16 + c15;
    const unsigned abase = (unsigned)((trc * 512 + hi * 32) ^ ((trc & 7) << 4));
    const int il_l = wr * 4 + hi;            // this lane's i within the tile

    float rmax[4][4];
#pragma unroll
    for (int n = 0; n < 4; ++n)
#pragma unroll
        for (int rg = 0; rg < 4; ++rg) rmax[n][rg] = -BIGN;

    for (int it = 0; it < nt; ++it) {
        // ---- epilogue operands for THIS tile (5 vmem, consumed post-MFMA)
        const int ig = ibase + it * 8 + il_l;
        f32x4 a4 = *(const f32x4*)(adj + (size_t)(b * N_ + ig) * N_ + j0);
        const float* mp = m2g + (size_t)(b * N_ + ig) * 128 + wn * 64 + c15;
        float mv0 = mp[0], mv1 = mp[16], mv2 = mp[32], mv3 = mp[48];

        // ---- stage NEXT tile into pb (stays in flight across barrier+MFMA)
        if (it + 1 < nt) {
            size_t toff = (size_t)(it + 1) * (8u * N_ * E_ * 4u);
            GL16(gq0 + toff, pb + woff);
            GL16(gq1 + toff, pb + woff + 1024);
            GL16(gq2 + toff, pb + woff + 2048);
            GL16(gq3 + toff, pb + woff + 3072);
            asm volatile("s_waitcnt vmcnt(9)" ::: "memory");  // tile it landed
        } else {
            asm volatile("s_waitcnt vmcnt(5)" ::: "memory");
        }
        __builtin_amdgcn_s_barrier();
        __builtin_amdgcn_sched_barrier(0);

        // ---- compute tile it from pa: ds_read f32 -> cvt -> 16 MFMA ----
        f32x4 acc[4] = {};
#pragma unroll
        for (int ks = 0; ks < 4; ++ks) {
            f32x4 lo = *(const f32x4*)(pa + (abase + ks * 128));
            f32x4 h4 = *(const f32x4*)(pa + ((abase ^ 16) + ks * 128));
            bf16x8 af = mk_frag(lo, h4);
#pragma unroll
            for (int n = 0; n < 4; ++n)
                acc[n] = __builtin_amdgcn_mfma_f32_16x16x32_bf16(
                    af, bfr[n][ks], acc[n], 0, 0, 0);
        }

        // ---- masked running max (rg == jj) ----
        float mvs[4] = {mv0, mv1, mv2, mv3};
#pragma unroll
        for (int n = 0; n < 4; ++n)
#pragma unroll
            for (int rg = 0; rg < 4; ++rg) {
                float v = acc[n][rg] + mvs[n];
                v = (a4[rg] > 0.0f) ? v : -BIGN;
                rmax[n][rg] = fmaxf(rmax[n][rg], v);
            }

        char* tp = pa; pa = pb; pb = pc; pc = tp;   // rotate ring
    }

    // ---- reduce over hi (i within wave), then across wr waves ----
#pragma unroll
    for (int n = 0; n < 4; ++n)
#pragma unroll
        for (int rg = 0; rg < 4; ++rg) {
            float v = rmax[n][rg];
            v = fmaxf(v, __shfl_xor(v, 16, 64));
            v = fmaxf(v, __shfl_xor(v, 32, 64));
            rmax[n][rg] = v;
        }
    __syncthreads();
    float* redb = (float*)smem;
    if (wr == 0 && lane < 16) {
#pragma unroll
        for (int n = 0; n < 4; ++n)
#pragma unroll
            for (int rg = 0; rg < 4; ++rg)
                redb[rg * 128 + wn * 64 + n * 16 + c15] = rmax[n][rg];
    }
    __syncthreads();
    if (wr == 1 && lane < 16) {
#pragma unroll
        for (int n = 0; n < 4; ++n)
#pragma unroll
            for (int rg = 0; rg < 4; ++rg) {
                int e = rg * 128 + wn * 64 + n * 16 + c15;
                redb[e] = fmaxf(redb[e], rmax[n][rg]);
            }
    }
    __syncthreads();
    for (int e = t; e < 512; e += 256)
        redp[(size_t)blk * 512 + e] = redb[e];
}

// ---------------------------------------------------------------------------
// finish: red = max over parts; out = relu(zo1 + (red+msg1+be)@Wo2 + bo2)
// ---------------------------------------------------------------------------
__global__ __launch_bounds__(256) void finish_kernel(
    const float* __restrict__ redp, const float* __restrict__ msg1,
    const float* __restrict__ zo1, const float* __restrict__ be,
    const float* __restrict__ Wo2, const float* __restrict__ bo2,
    float* __restrict__ out, int nsplit)
{
    __shared__ float rb[8][128];
    const int t  = threadIdx.x;
    const int r0 = blockIdx.x * 8;

    for (int idx = t; idx < 1024; idx += 256) {
        int rr = idx >> 7, k = idx & 127;
        int r = r0 + rr;
        int jblk = r >> 2, jj = r & 3;
        float v = -BIGN - 1.0f;
        for (int p = 0; p < nsplit; ++p)
            v = fmaxf(v, redp[(size_t)(jblk * nsplit + p) * 512 + jj * 128 + k]);
        rb[rr][k] = v + msg1[(size_t)r * 128 + k] + be[k];
    }
    __syncthreads();

    const int col = t & 127;
    const int half = t >> 7;
#pragma unroll
    for (int rx = 0; rx < 4; ++rx) {
        int rr = half * 4 + rx;
        size_t row = (size_t)(r0 + rr);
        float a = 0.0f;
#pragma unroll 8
        for (int k = 0; k < 128; ++k)
            a = fmaf(rb[rr][k], Wo2[k * 128 + col], a);
        float o = zo1[row * 128 + col] + bo2[col] + a;
        out[row * 128 + col] = fmaxf(o, 0.0f);
    }
}

extern "C" void kernel_launch(void* const* d_in, const int* in_sizes, int n_in,
                              void* d_out, int out_size, void* d_ws, size_t ws_size,
                              hipStream_t stream) {
    const float* node   = (const float*)d_in[0];
    const float* edge   = (const float*)d_in[1];
    const float* gf     = (const float*)d_in[2];
    const float* adj    = (const float*)d_in[3];
    const float* hidden = (const float*)d_in[4];
    const float* W1  = (const float*)d_in[5];
    const float* b1  = (const float*)d_in[6];
    const float* W2  = (const float*)d_in[7];
    const float* b2  = (const float*)d_in[8];
    const float* We  = (const float*)d_in[9];
    const float* be  = (const float*)d_in[10];
    const float* Wg  = (const float*)d_in[11];
    const float* bg  = (const float*)d_in[12];
    const float* Wo1 = (const float*)d_in[13];
    const float* bo1 = (const float*)d_in[14];
    const float* Wo2 = (const float*)d_in[15];
    const float* bo2 = (const float*)d_in[16];
    float* out = (float*)d_out;

    float* msg1 = (float*)d_ws;                                   // 1 MB
    float* m2g  = msg1 + 2048 * 128;                              // 1 MB
    float* zo1  = m2g + 2048 * 128;                               // 1 MB
    unsigned short* weT = (unsigned short*)(zo1 + 2048 * 128);    // 32 KB
    float* redp = (float*)((char*)weT + 128 * 128 * sizeof(unsigned short));

    const size_t base_bytes = 3u * 1048576u + 32768u;
    int nsplit = (ws_size >= base_bytes + 2u * 1048576u) ? 2 : 1;

    hipLaunchKernelGGL(prep_kernel, dim3(512), dim3(256), 0, stream,
                       node, hidden, gf, W1, b1, W2, b2, Wg, bg, Wo1, bo1, We,
                       msg1, m2g, zo1, weT);
    hipLaunchKernelGGL(pgn_main, dim3(512 * nsplit), dim3(256), 0, stream,
                       edge, adj, m2g, weT, redp, nsplit);
    hipLaunchKernelGGL(finish_kernel, dim3(256), dim3(256), 0, stream,
                       redp, msg1, zo1, be, Wo2, bo2, out, nsplit);
}